// Round 17
// baseline (267.536 us; speedup 1.0000x reference)
//
#include <hip/hip_runtime.h>
#include <hip/hip_bf16.h>
#include <stdint.h>

typedef __attribute__((ext_vector_type(4)))  float   f32x4;
typedef __attribute__((ext_vector_type(16))) float   f32x16;
typedef __attribute__((ext_vector_type(8)))  __bf16  bf16x8;
typedef __attribute__((ext_vector_type(8)))  short   s16x8;
typedef __attribute__((ext_vector_type(4)))  unsigned short u16x4;
typedef __attribute__((ext_vector_type(4)))  float   fl4;
typedef __attribute__((ext_vector_type(2)))  unsigned int u32x2;
typedef __attribute__((ext_vector_type(4)))  unsigned int u32x4;

#define DEVFN static __device__ __forceinline__

constexpr int BATCH = 2, SEQ = 2048, HID = 2048, NHEAD = 16, HDIM = 128;
constexpr int MROWS = BATCH * SEQ;   // 4096
constexpr int N3    = 3 * HID;       // 6144
constexpr float LOG2E = 1.44269504088896340736f;
constexpr float SCALE_LOG2E = 0.12751649736170852f;   // (1/sqrt(128)) * log2(e)
constexpr float DEFER_THR = 11.541560327111708f;      // 8 * log2(e)

DEVFN unsigned short f2bf(float f) {  // RNE float->bf16
  unsigned int u = __float_as_uint(f);
  u += 0x7FFFu + ((u >> 16) & 1u);
  return (unsigned short)(u >> 16);
}

DEVFN void async_cp16(const void* g, void* l) {
  __builtin_amdgcn_global_load_lds(
      (__attribute__((address_space(1))) void*)g,
      (__attribute__((address_space(3))) void*)l, 16, 0, 0);
}

DEVFN f32x4 mfma_bf16(bf16x8 a, bf16x8 b, f32x4 c) {
  return __builtin_amdgcn_mfma_f32_16x16x32_bf16(a, b, c, 0, 0, 0);
}
DEVFN f32x16 mfma32(bf16x8 a, bf16x8 b, f32x16 c) {
  return __builtin_amdgcn_mfma_f32_32x32x16_bf16(a, b, c, 0, 0, 0);
}
DEVFN unsigned cvt_pk_bf16(float lo, float hi) {
  unsigned r;
  asm("v_cvt_pk_bf16_f32 %0, %1, %2" : "=v"(r) : "v"(lo), "v"(hi));
  return r;
}

// ---------------------------------------------------------------- fused prep (proven r16)
__global__ __launch_bounds__(256) void prep_kernel(const float* __restrict__ hs,
                                                   unsigned short* __restrict__ hs_bf,
                                                   const float* __restrict__ Wqkv,
                                                   unsigned short* __restrict__ wq_bf,
                                                   const float* __restrict__ Wout,
                                                   unsigned short* __restrict__ wo_bf) {
  __shared__ float tile[32][33];
  const int blk = blockIdx.x;
  const int tid = threadIdx.x;
  if (blk < 2048) {
    constexpr int n4 = MROWS * HID / 4;
    for (int i = blk * 256 + tid; i < n4; i += 2048 * 256) {
      fl4 v = ((const fl4*)hs)[i];
      u16x4 hh;
#pragma unroll
      for (int j = 0; j < 4; j++) hh[j] = f2bf(v[j]);
      ((u16x4*)hs_bf)[i] = hh;
    }
    return;
  }
  const bool isQ = blk < 2048 + 12288;
  const int t = isQ ? (blk - 2048) : (blk - 2048 - 12288);
  const int nbx = isQ ? (N3 / 32) : (HID / 32);
  const int C = isQ ? N3 : HID;
  const int R = HID;
  const float* W = isQ ? Wqkv : Wout;
  unsigned short* T = isQ ? wq_bf : wo_bf;
  const int c0 = (t % nbx) * 32, r0 = (t / nbx) * 32;
  const int tx = tid & 31, ty = tid >> 5;
#pragma unroll
  for (int i = 0; i < 4; i++) tile[ty + 8 * i][tx] = W[(size_t)(r0 + ty + 8 * i) * C + c0 + tx];
  __syncthreads();
#pragma unroll
  for (int i = 0; i < 4; i++) {
    const float v = tile[tx][ty + 8 * i];
    T[(size_t)(c0 + ty + 8 * i) * R + r0 + tx] = f2bf(v);
  }
}

// ---------------------------------------------------------------- ring-pipelined GEMM (proven r11)
// + T1 XCD-aware block swizzle: XCD k owns contiguous chunk of blocks ->
//   A-panels become L2-resident per XCD (bijective: nwg % 8 == 0 for both launches).
template <bool OUT_BF16>
__global__ __launch_bounds__(512, 1) void gemm_ring(const unsigned short* __restrict__ A,
                                                    const unsigned short* __restrict__ Bt,
                                                    const float* __restrict__ bias,
                                                    void* __restrict__ Cout, int Ndim) {
  constexpr int KDIM  = 2048;
  constexpr int NT    = KDIM / 64;
  constexpr int ASLOT = 256 * 64;
  constexpr int BSLOT = 128 * 64;
  constexpr int SLOT  = ASLOT + BSLOT;
  __shared__ __align__(16) unsigned short smem[3 * SLOT];  // 144 KB

  const int tid = threadIdx.x;
  const int wid = tid >> 6, lane = tid & 63;
  const int wm = wid >> 2, wn = wid & 3;
  const int g = lane >> 4, q = lane & 15;

  // T1 swizzle: linear bid -> per-XCD contiguous chunk
  const int nx  = gridDim.x;
  const int nwg = nx * gridDim.y;
  const int lbid = blockIdx.y * nx + blockIdx.x;
  const int cpx = nwg >> 3;                       // nwg % 8 == 0 (768 / 256)
  const int nbid = (lbid & 7) * cpx + (lbid >> 3);
  const int n0 = (nbid % nx) * 128, m0 = (nbid / nx) * 256;

  const int srow = (wid << 3) + (lane >> 3);
  const int scol = (((lane & 7) ^ (lane >> 3)) << 4);
  const char* gA = (const char*)A  + ((size_t)(m0 + srow) * KDIM) * 2 + scol;
  const char* gB = (const char*)Bt + ((size_t)(n0 + srow) * KDIM) * 2 + scol;
  const int dbase = ((wid << 3)) << 7;

  f32x4 acc[8][2] = {};
  const int axor = (q & 7) << 4;

  auto STAGE = [&](int tt, int slot) {
    char* sA = (char*)(smem + slot * SLOT);
    char* sB = (char*)(smem + slot * SLOT + ASLOT);
    const size_t koff = (size_t)tt << 7;
#pragma unroll
    for (int i = 0; i < 4; i++)
      async_cp16(gA + (size_t)(i * 64) * (KDIM * 2) + koff, sA + dbase + (i << 13));
#pragma unroll
    for (int i = 0; i < 2; i++)
      async_cp16(gB + (size_t)(i * 64) * (KDIM * 2) + koff, sB + dbase + (i << 13));
  };

  auto COMPUTE = [&](int slot) {
    const char* sA = (const char*)(smem + slot * SLOT);
    const char* sB = (const char*)(smem + slot * SLOT + ASLOT);
#pragma unroll
    for (int ks = 0; ks < 2; ks++) {
      const int kb = (ks << 6) + (g << 4);
      bf16x8 av[8], bv[2];
#pragma unroll
      for (int nf = 0; nf < 2; nf++) {
        const int row = (wn << 5) + (nf << 4) + q;
        bv[nf] = *(const bf16x8*)(sB + (row << 7) + (kb ^ axor));
      }
#pragma unroll
      for (int mf = 0; mf < 8; mf++) {
        const int row = (wm << 7) + (mf << 4) + q;
        av[mf] = *(const bf16x8*)(sA + (row << 7) + (kb ^ axor));
      }
#pragma unroll
      for (int mf = 0; mf < 8; mf++)
#pragma unroll
        for (int nf = 0; nf < 2; nf++)
          acc[mf][nf] = mfma_bf16(av[mf], bv[nf], acc[mf][nf]);
    }
  };

  STAGE(0, 0);
  STAGE(1, 1);
  int s2 = 2, sc = 0;
#pragma unroll 1
  for (int t = 0; t < NT - 2; ++t) {
    asm volatile("s_waitcnt vmcnt(6)" ::: "memory");
    __builtin_amdgcn_s_barrier();
    asm volatile("" ::: "memory");
    STAGE(t + 2, s2);
    COMPUTE(sc);
    s2 = (s2 == 2) ? 0 : s2 + 1;
    sc = (sc == 2) ? 0 : sc + 1;
  }
  asm volatile("s_waitcnt vmcnt(6)" ::: "memory");
  __builtin_amdgcn_s_barrier();
  asm volatile("" ::: "memory");
  COMPUTE(sc);
  sc = (sc == 2) ? 0 : sc + 1;
  asm volatile("s_waitcnt vmcnt(0)" ::: "memory");
  __builtin_amdgcn_s_barrier();
  asm volatile("" ::: "memory");
  COMPUTE(sc);

  float bvv[2];
#pragma unroll
  for (int nf = 0; nf < 2; nf++) bvv[nf] = bias[n0 + (wn << 5) + (nf << 4) + q];
#pragma unroll
  for (int mf = 0; mf < 8; mf++) {
    const int rowg = m0 + (wm << 7) + (mf << 4) + (g << 2);
#pragma unroll
    for (int nf = 0; nf < 2; nf++) {
      const int colg = n0 + (wn << 5) + (nf << 4) + q;
#pragma unroll
      for (int r = 0; r < 4; r++) {
        const float v = acc[mf][nf][r] + bvv[nf];
        if (OUT_BF16)
          ((unsigned short*)Cout)[(size_t)(rowg + r) * Ndim + colg] = f2bf(v);
        else
          ((float*)Cout)[(size_t)(rowg + r) * Ndim + colg] = v;
      }
    }
  }
}

// ---------------------------------------------------------------- V slice of QKV -> V^T [z][d][s]
__global__ __launch_bounds__(256) void transpose_v(const unsigned short* __restrict__ qkv,
                                                   unsigned short* __restrict__ vt) {
  __shared__ __align__(16) unsigned short tile[64][136];
  const int z = blockIdx.y, b = z >> 4, h = z & 15;
  const int s0 = blockIdx.x << 6;
  const int t = threadIdx.x;
#pragma unroll
  for (int i = 0; i < 4; i++) {
    const int idx = t + (i << 8);
    const int row = idx >> 4, ch = idx & 15;
    *(s16x8*)&tile[row][ch << 3] =
        *(const s16x8*)(qkv + (size_t)(b * SEQ + s0 + row) * N3 + 2 * HID + h * HDIM + (ch << 3));
  }
  __syncthreads();
#pragma unroll
  for (int i = 0; i < 4; i++) {
    const int idx = t + (i << 8);
    const int d = idx >> 3, sc = idx & 7;
    s16x8 v;
#pragma unroll
    for (int j = 0; j < 8; j++) v[j] = (short)tile[(sc << 3) + j][d];
    *(s16x8*)(vt + (size_t)(z * HDIM + d) * SEQ + s0 + (sc << 3)) = v;
  }
}

// ---------------------------------------------------------------- flash attention v3 (proven r11)
__global__ __launch_bounds__(256, 2) void attn_kernel(const unsigned short* __restrict__ qkv,
                                                      const unsigned short* __restrict__ vt,
                                                      const float* __restrict__ mask,
                                                      unsigned short* __restrict__ ctx) {
  constexpr int NT    = SEQ / 64;
  constexpr int KSLOT = 64 * 128;
  constexpr int VSLOT = 64 * 128;
  constexpr int SLOT  = KSLOT + VSLOT;
  __shared__ __align__(16) unsigned short sKV[2 * SLOT];   // 64 KB
  __shared__ __align__(16) float sM[SEQ];                  // 8 KB

  const int bid = blockIdx.x;
  const int idx = bid >> 3;
  const int z  = ((bid & 7) << 2) + (idx >> 4);
  const int qb = idx & 15;
  const int b = z >> 4, h = z & 15;
  const int tid = threadIdx.x, wid = tid >> 6, lane = tid & 63;
  const int l31 = lane & 31, hi = lane >> 5;
  const int q0w = (qb << 7) + (wid << 5);

#pragma unroll
  for (int j = 0; j < 2; j++) {
    fl4 m = ((const fl4*)(mask + (size_t)b * SEQ))[tid + (j << 8)];
    m *= LOG2E;
    ((fl4*)sM)[tid + (j << 8)] = m;
  }

  bf16x8 bq[8];
  {
    const char* qrow = (const char*)(qkv + (size_t)(b * SEQ + q0w + l31) * N3 + h * HDIM);
#pragma unroll
    for (int kc = 0; kc < 8; kc++) bq[kc] = *(const bf16x8*)(qrow + (kc << 5) + (hi << 4));
  }

  f32x16 acc2[4] = {};
  float mrun = -1e30f, lrun = 0.f;

  const char* gK = (const char*)qkv + ((size_t)(b * SEQ) * N3 + HID + h * HDIM) * 2;
  const char* gV = (const char*)vt + ((size_t)z * HDIM * SEQ) * 2;

  auto STAGE = [&](int tt, int slot) {
    char* kb_ = (char*)(sKV + slot * SLOT);
    char* vb_ = kb_ + KSLOT * 2;
    const int k0 = tt << 6;
#pragma unroll
    for (int i = 0; i < 4; i++) {
      const int row = (i << 4) + (wid << 2) + (lane >> 4);
      const int sl  = lane & 15;
      const int dst = (i << 12) + (wid << 10);
      async_cp16(gK + ((size_t)(k0 + row) * N3) * 2 + (((sl ^ (row & 15))) << 4), kb_ + dst);
      const int sv  = sl ^ (row & 15);
      const int dhi = sv >> 3, kc8 = sv & 7;
      async_cp16(gV + ((size_t)((dhi << 6) + row) * SEQ + k0 + (kc8 << 3)) * 2, vb_ + dst);
    }
  };

  auto COMPUTE = [&](int t, int slot) {
    const char* sK = (const char*)(sKV + slot * SLOT);
    const char* sV = (const char*)(sKV + slot * SLOT + KSLOT);
    const int k0 = t << 6;

    f32x16 accs[2] = {};
    __builtin_amdgcn_s_setprio(1);
#pragma unroll
    for (int kb = 0; kb < 2; kb++)
#pragma unroll
      for (int kc = 0; kc < 8; kc++) {
        const int key = (kb << 5) + l31;
        const bf16x8 ka = *(const bf16x8*)(sK + (key << 8) +
                                           ((((kc << 1) + hi) ^ (l31 & 15)) << 4));
        accs[kb] = mfma32(ka, bq[kc], accs[kb]);
      }
    __builtin_amdgcn_s_setprio(0);

    float p_[2][16];
#pragma unroll
    for (int kb = 0; kb < 2; kb++) {
      fl4 mk[4];
#pragma unroll
      for (int m = 0; m < 4; m++) mk[m] = *(const fl4*)&sM[k0 + (kb << 5) + (m << 3) + (hi << 2)];
#pragma unroll
      for (int r = 0; r < 16; r++)
        p_[kb][r] = fmaf(accs[kb][r], SCALE_LOG2E, mk[r >> 2][r & 3]);
    }
    float mt = p_[0][0];
#pragma unroll
    for (int kb = 0; kb < 2; kb++)
#pragma unroll
      for (int r = 0; r < 16; r++) mt = fmaxf(mt, p_[kb][r]);
    mt = fmaxf(mt, __shfl_xor(mt, 32));
    if (!__all(mt <= mrun + DEFER_THR)) {
      const float mnew = fmaxf(mrun, mt);
      const float fs = exp2f(mrun - mnew);
      lrun *= fs;
#pragma unroll
      for (int r = 0; r < 16; r++) {
        const int qr = (r & 3) + ((r >> 2) << 3) + (hi << 2);
        const float fr = __shfl(fs, (lane & 32) | qr);
#pragma unroll
        for (int db = 0; db < 4; db++) acc2[db][r] *= fr;
      }
      mrun = mnew;
    }
    float ps = 0.f;
#pragma unroll
    for (int kb = 0; kb < 2; kb++)
#pragma unroll
      for (int r = 0; r < 16; r++) {
        const float e = exp2f(p_[kb][r] - mrun);
        p_[kb][r] = e;
        ps += e;
      }
    ps += __shfl_xor(ps, 32);
    lrun += ps;

    bf16x8 pa[4];
#pragma unroll
    for (int kb = 0; kb < 2; kb++)
#pragma unroll
      for (int hh = 0; hh < 2; hh++) {
        const float* pp = &p_[kb][hh << 3];
        const unsigned x01 = cvt_pk_bf16(pp[0], pp[1]);
        const unsigned x23 = cvt_pk_bf16(pp[2], pp[3]);
        const unsigned y01 = cvt_pk_bf16(pp[4], pp[5]);
        const unsigned y23 = cvt_pk_bf16(pp[6], pp[7]);
        const u32x2 sa = __builtin_amdgcn_permlane32_swap(x01, y01, false, false);
        const u32x2 sb = __builtin_amdgcn_permlane32_swap(x23, y23, false, false);
        const u32x4 w = {sa[0], sb[0], sa[1], sb[1]};
        pa[(kb << 1) + hh] = __builtin_bit_cast(bf16x8, w);
      }

    __builtin_amdgcn_s_setprio(1);
#pragma unroll
    for (int db = 0; db < 4; db++) {
      const int dd = ((db & 1) << 5) + l31;
#pragma unroll
      for (int ks = 0; ks < 4; ks++) {
        const int sv = ((db >> 1) << 3) + (ks << 1) + hi;
        const bf16x8 bv = *(const bf16x8*)(sV + (dd << 8) + ((sv ^ (l31 & 15)) << 4));
        acc2[db] = mfma32(pa[ks], bv, acc2[db]);
      }
    }
    __builtin_amdgcn_s_setprio(0);
  };

  STAGE(0, 0);
  __syncthreads();
#pragma unroll 1
  for (int t = 0; t < NT - 1; ++t) {
    STAGE(t + 1, (t + 1) & 1);
    COMPUTE(t, t & 1);
    asm volatile("s_waitcnt vmcnt(0)" ::: "memory");
    __builtin_amdgcn_s_barrier();
    asm volatile("" ::: "memory");
  }
  COMPUTE(NT - 1, (NT - 1) & 1);

  const float inv = 1.f / lrun;
#pragma unroll
  for (int r = 0; r < 16; r++) {
    const int qr = (r & 3) + ((r >> 2) << 3) + (hi << 2);
    const float fr = __shfl(inv, (lane & 32) | qr);
    unsigned short* crow = ctx + (size_t)(b * SEQ + q0w + qr) * HID + h * HDIM + l31;
#pragma unroll
    for (int db = 0; db < 4; db++) crow[db << 5] = f2bf(acc2[db][r] * fr);
  }
}

// ---------------------------------------------------------------- launch
extern "C" void kernel_launch(void* const* d_in, const int* in_sizes, int n_in,
                              void* d_out, int out_size, void* d_ws, size_t ws_size,
                              hipStream_t stream) {
  const float* hs   = (const float*)d_in[0];
  const float* mask = (const float*)d_in[1];
  const float* Wqkv = (const float*)d_in[2];
  const float* bqkv = (const float*)d_in[3];
  const float* Wout = (const float*)d_in[4];
  const float* bout = (const float*)d_in[5];

  char* ws = (char*)d_ws;
  size_t off = 0;
  auto alloc = [&](size_t n) { char* p = ws + off; off += (n + 255) & ~(size_t)255; return p; };
  unsigned short* hs_bf = (unsigned short*)alloc((size_t)MROWS * HID * 2);
  unsigned short* wq_bf = (unsigned short*)alloc((size_t)N3 * HID * 2);
  unsigned short* wo_bf = (unsigned short*)alloc((size_t)HID * HID * 2);
  unsigned short* qkvb  = (unsigned short*)alloc((size_t)MROWS * N3 * 2);
  unsigned short* vtb   = (unsigned short*)alloc((size_t)BATCH * NHEAD * HDIM * SEQ * 2);
  unsigned short* ctxb  = (unsigned short*)alloc((size_t)MROWS * HID * 2);
  (void)ws_size;

  prep_kernel<<<2048 + 12288 + 4096, 256, 0, stream>>>(hs, hs_bf, Wqkv, wq_bf, Wout, wo_bf);
  gemm_ring<true ><<<dim3(N3 / 128, MROWS / 256), 512, 0, stream>>>(hs_bf, wq_bf, bqkv, qkvb, N3);
  transpose_v<<<dim3(SEQ / 64, BATCH * NHEAD), 256, 0, stream>>>(qkvb, vtb);
  attn_kernel<<<512, 256, 0, stream>>>(qkvb, vtb, mask, ctxb);
  gemm_ring<false><<<dim3(HID / 128, MROWS / 256), 512, 0, stream>>>(ctxb, wo_bf, bout, (float*)d_out, HID);
}

// Round 18
// 262.126 us; speedup vs baseline: 1.0206x; 1.0206x over previous
//
#include <hip/hip_runtime.h>
#include <hip/hip_bf16.h>
#include <stdint.h>

typedef __attribute__((ext_vector_type(4)))  float   f32x4;
typedef __attribute__((ext_vector_type(16))) float   f32x16;
typedef __attribute__((ext_vector_type(8)))  __bf16  bf16x8;
typedef __attribute__((ext_vector_type(8)))  short   s16x8;
typedef __attribute__((ext_vector_type(4)))  unsigned short u16x4;
typedef __attribute__((ext_vector_type(4)))  float   fl4;
typedef __attribute__((ext_vector_type(2)))  unsigned int u32x2;
typedef __attribute__((ext_vector_type(4)))  unsigned int u32x4;

#define DEVFN static __device__ __forceinline__

constexpr int BATCH = 2, SEQ = 2048, HID = 2048, NHEAD = 16, HDIM = 128;
constexpr int MROWS = BATCH * SEQ;   // 4096
constexpr int N3    = 3 * HID;       // 6144
constexpr float LOG2E = 1.44269504088896340736f;
constexpr float SCALE_LOG2E = 0.12751649736170852f;   // (1/sqrt(128)) * log2(e)
constexpr float DEFER_THR = 11.541560327111708f;      // 8 * log2(e)

DEVFN unsigned short f2bf(float f) {  // RNE float->bf16
  unsigned int u = __float_as_uint(f);
  u += 0x7FFFu + ((u >> 16) & 1u);
  return (unsigned short)(u >> 16);
}

DEVFN void async_cp16(const void* g, void* l) {
  __builtin_amdgcn_global_load_lds(
      (__attribute__((address_space(1))) void*)g,
      (__attribute__((address_space(3))) void*)l, 16, 0, 0);
}

DEVFN f32x4 mfma_bf16(bf16x8 a, bf16x8 b, f32x4 c) {
  return __builtin_amdgcn_mfma_f32_16x16x32_bf16(a, b, c, 0, 0, 0);
}
DEVFN f32x16 mfma32(bf16x8 a, bf16x8 b, f32x16 c) {
  return __builtin_amdgcn_mfma_f32_32x32x16_bf16(a, b, c, 0, 0, 0);
}
DEVFN unsigned cvt_pk_bf16(float lo, float hi) {
  unsigned r;
  asm("v_cvt_pk_bf16_f32 %0, %1, %2" : "=v"(r) : "v"(lo), "v"(hi));
  return r;
}

// ---------------------------------------------------------------- fused prep (proven r16)
__global__ __launch_bounds__(256) void prep_kernel(const float* __restrict__ hs,
                                                   unsigned short* __restrict__ hs_bf,
                                                   const float* __restrict__ Wqkv,
                                                   unsigned short* __restrict__ wq_bf,
                                                   const float* __restrict__ Wout,
                                                   unsigned short* __restrict__ wo_bf) {
  __shared__ float tile[32][33];
  const int blk = blockIdx.x;
  const int tid = threadIdx.x;
  if (blk < 2048) {
    constexpr int n4 = MROWS * HID / 4;
    for (int i = blk * 256 + tid; i < n4; i += 2048 * 256) {
      fl4 v = ((const fl4*)hs)[i];
      u16x4 hh;
#pragma unroll
      for (int j = 0; j < 4; j++) hh[j] = f2bf(v[j]);
      ((u16x4*)hs_bf)[i] = hh;
    }
    return;
  }
  const bool isQ = blk < 2048 + 12288;
  const int t = isQ ? (blk - 2048) : (blk - 2048 - 12288);
  const int nbx = isQ ? (N3 / 32) : (HID / 32);
  const int C = isQ ? N3 : HID;
  const int R = HID;
  const float* W = isQ ? Wqkv : Wout;
  unsigned short* T = isQ ? wq_bf : wo_bf;
  const int c0 = (t % nbx) * 32, r0 = (t / nbx) * 32;
  const int tx = tid & 31, ty = tid >> 5;
#pragma unroll
  for (int i = 0; i < 4; i++) tile[ty + 8 * i][tx] = W[(size_t)(r0 + ty + 8 * i) * C + c0 + tx];
  __syncthreads();
#pragma unroll
  for (int i = 0; i < 4; i++) {
    const float v = tile[tx][ty + 8 * i];
    T[(size_t)(c0 + ty + 8 * i) * R + r0 + tx] = f2bf(v);
  }
}

// ---------------------------------------------------------------- ring-pipelined GEMM (proven r11/r16)
template <bool OUT_BF16>
__global__ __launch_bounds__(512, 1) void gemm_ring(const unsigned short* __restrict__ A,
                                                    const unsigned short* __restrict__ Bt,
                                                    const float* __restrict__ bias,
                                                    void* __restrict__ Cout, int Ndim) {
  constexpr int KDIM  = 2048;
  constexpr int NT    = KDIM / 64;
  constexpr int ASLOT = 256 * 64;
  constexpr int BSLOT = 128 * 64;
  constexpr int SLOT  = ASLOT + BSLOT;
  __shared__ __align__(16) unsigned short smem[3 * SLOT];  // 144 KB

  const int tid = threadIdx.x;
  const int wid = tid >> 6, lane = tid & 63;
  const int wm = wid >> 2, wn = wid & 3;
  const int g = lane >> 4, q = lane & 15;
  const int n0 = blockIdx.x * 128, m0 = blockIdx.y * 256;

  const int srow = (wid << 3) + (lane >> 3);
  const int scol = (((lane & 7) ^ (lane >> 3)) << 4);
  const char* gA = (const char*)A  + ((size_t)(m0 + srow) * KDIM) * 2 + scol;
  const char* gB = (const char*)Bt + ((size_t)(n0 + srow) * KDIM) * 2 + scol;
  const int dbase = ((wid << 3)) << 7;

  f32x4 acc[8][2] = {};
  const int axor = (q & 7) << 4;

  auto STAGE = [&](int tt, int slot) {
    char* sA = (char*)(smem + slot * SLOT);
    char* sB = (char*)(smem + slot * SLOT + ASLOT);
    const size_t koff = (size_t)tt << 7;
#pragma unroll
    for (int i = 0; i < 4; i++)
      async_cp16(gA + (size_t)(i * 64) * (KDIM * 2) + koff, sA + dbase + (i << 13));
#pragma unroll
    for (int i = 0; i < 2; i++)
      async_cp16(gB + (size_t)(i * 64) * (KDIM * 2) + koff, sB + dbase + (i << 13));
  };

  auto COMPUTE = [&](int slot) {
    const char* sA = (const char*)(smem + slot * SLOT);
    const char* sB = (const char*)(smem + slot * SLOT + ASLOT);
#pragma unroll
    for (int ks = 0; ks < 2; ks++) {
      const int kb = (ks << 6) + (g << 4);
      bf16x8 av[8], bv[2];
#pragma unroll
      for (int nf = 0; nf < 2; nf++) {
        const int row = (wn << 5) + (nf << 4) + q;
        bv[nf] = *(const bf16x8*)(sB + (row << 7) + (kb ^ axor));
      }
#pragma unroll
      for (int mf = 0; mf < 8; mf++) {
        const int row = (wm << 7) + (mf << 4) + q;
        av[mf] = *(const bf16x8*)(sA + (row << 7) + (kb ^ axor));
      }
#pragma unroll
      for (int mf = 0; mf < 8; mf++)
#pragma unroll
        for (int nf = 0; nf < 2; nf++)
          acc[mf][nf] = mfma_bf16(av[mf], bv[nf], acc[mf][nf]);
    }
  };

  STAGE(0, 0);
  STAGE(1, 1);
  int s2 = 2, sc = 0;
#pragma unroll 1
  for (int t = 0; t < NT - 2; ++t) {
    asm volatile("s_waitcnt vmcnt(6)" ::: "memory");
    __builtin_amdgcn_s_barrier();
    asm volatile("" ::: "memory");
    STAGE(t + 2, s2);
    COMPUTE(sc);
    s2 = (s2 == 2) ? 0 : s2 + 1;
    sc = (sc == 2) ? 0 : sc + 1;
  }
  asm volatile("s_waitcnt vmcnt(6)" ::: "memory");
  __builtin_amdgcn_s_barrier();
  asm volatile("" ::: "memory");
  COMPUTE(sc);
  sc = (sc == 2) ? 0 : sc + 1;
  asm volatile("s_waitcnt vmcnt(0)" ::: "memory");
  __builtin_amdgcn_s_barrier();
  asm volatile("" ::: "memory");
  COMPUTE(sc);

  float bvv[2];
#pragma unroll
  for (int nf = 0; nf < 2; nf++) bvv[nf] = bias[n0 + (wn << 5) + (nf << 4) + q];
#pragma unroll
  for (int mf = 0; mf < 8; mf++) {
    const int rowg = m0 + (wm << 7) + (mf << 4) + (g << 2);
#pragma unroll
    for (int nf = 0; nf < 2; nf++) {
      const int colg = n0 + (wn << 5) + (nf << 4) + q;
#pragma unroll
      for (int r = 0; r < 4; r++) {
        const float v = acc[mf][nf][r] + bvv[nf];
        if (OUT_BF16)
          ((unsigned short*)Cout)[(size_t)(rowg + r) * Ndim + colg] = f2bf(v);
        else
          ((float*)Cout)[(size_t)(rowg + r) * Ndim + colg] = v;
      }
    }
  }
}

// ---------------------------------------------------------------- V slice of QKV -> V^T [z][d][s]
__global__ __launch_bounds__(256) void transpose_v(const unsigned short* __restrict__ qkv,
                                                   unsigned short* __restrict__ vt) {
  __shared__ __align__(16) unsigned short tile[64][136];
  const int z = blockIdx.y, b = z >> 4, h = z & 15;
  const int s0 = blockIdx.x << 6;
  const int t = threadIdx.x;
#pragma unroll
  for (int i = 0; i < 4; i++) {
    const int idx = t + (i << 8);
    const int row = idx >> 4, ch = idx & 15;
    *(s16x8*)&tile[row][ch << 3] =
        *(const s16x8*)(qkv + (size_t)(b * SEQ + s0 + row) * N3 + 2 * HID + h * HDIM + (ch << 3));
  }
  __syncthreads();
#pragma unroll
  for (int i = 0; i < 4; i++) {
    const int idx = t + (i << 8);
    const int d = idx >> 3, sc = idx & 7;
    s16x8 v;
#pragma unroll
    for (int j = 0; j < 8; j++) v[j] = (short)tile[(sc << 3) + j][d];
    *(s16x8*)(vt + (size_t)(z * HDIM + d) * SEQ + s0 + (sc << 3)) = v;
  }
}

// ---------------------------------------------------------------- flash attention v3 (proven r11)
__global__ __launch_bounds__(256, 2) void attn_kernel(const unsigned short* __restrict__ qkv,
                                                      const unsigned short* __restrict__ vt,
                                                      const float* __restrict__ mask,
                                                      unsigned short* __restrict__ ctx) {
  constexpr int NT    = SEQ / 64;
  constexpr int KSLOT = 64 * 128;
  constexpr int VSLOT = 64 * 128;
  constexpr int SLOT  = KSLOT + VSLOT;
  __shared__ __align__(16) unsigned short sKV[2 * SLOT];   // 64 KB
  __shared__ __align__(16) float sM[SEQ];                  // 8 KB

  const int bid = blockIdx.x;
  const int idx = bid >> 3;
  const int z  = ((bid & 7) << 2) + (idx >> 4);
  const int qb = idx & 15;
  const int b = z >> 4, h = z & 15;
  const int tid = threadIdx.x, wid = tid >> 6, lane = tid & 63;
  const int l31 = lane & 31, hi = lane >> 5;
  const int q0w = (qb << 7) + (wid << 5);

#pragma unroll
  for (int j = 0; j < 2; j++) {
    fl4 m = ((const fl4*)(mask + (size_t)b * SEQ))[tid + (j << 8)];
    m *= LOG2E;
    ((fl4*)sM)[tid + (j << 8)] = m;
  }

  bf16x8 bq[8];
  {
    const char* qrow = (const char*)(qkv + (size_t)(b * SEQ + q0w + l31) * N3 + h * HDIM);
#pragma unroll
    for (int kc = 0; kc < 8; kc++) bq[kc] = *(const bf16x8*)(qrow + (kc << 5) + (hi << 4));
  }

  f32x16 acc2[4] = {};
  float mrun = -1e30f, lrun = 0.f;

  const char* gK = (const char*)qkv + ((size_t)(b * SEQ) * N3 + HID + h * HDIM) * 2;
  const char* gV = (const char*)vt + ((size_t)z * HDIM * SEQ) * 2;

  auto STAGE = [&](int tt, int slot) {
    char* kb_ = (char*)(sKV + slot * SLOT);
    char* vb_ = kb_ + KSLOT * 2;
    const int k0 = tt << 6;
#pragma unroll
    for (int i = 0; i < 4; i++) {
      const int row = (i << 4) + (wid << 2) + (lane >> 4);
      const int sl  = lane & 15;
      const int dst = (i << 12) + (wid << 10);
      async_cp16(gK + ((size_t)(k0 + row) * N3) * 2 + (((sl ^ (row & 15))) << 4), kb_ + dst);
      const int sv  = sl ^ (row & 15);
      const int dhi = sv >> 3, kc8 = sv & 7;
      async_cp16(gV + ((size_t)((dhi << 6) + row) * SEQ + k0 + (kc8 << 3)) * 2, vb_ + dst);
    }
  };

  auto COMPUTE = [&](int t, int slot) {
    const char* sK = (const char*)(sKV + slot * SLOT);
    const char* sV = (const char*)(sKV + slot * SLOT + KSLOT);
    const int k0 = t << 6;

    f32x16 accs[2] = {};
    __builtin_amdgcn_s_setprio(1);
#pragma unroll
    for (int kb = 0; kb < 2; kb++)
#pragma unroll
      for (int kc = 0; kc < 8; kc++) {
        const int key = (kb << 5) + l31;
        const bf16x8 ka = *(const bf16x8*)(sK + (key << 8) +
                                           ((((kc << 1) + hi) ^ (l31 & 15)) << 4));
        accs[kb] = mfma32(ka, bq[kc], accs[kb]);
      }
    __builtin_amdgcn_s_setprio(0);

    float p_[2][16];
#pragma unroll
    for (int kb = 0; kb < 2; kb++) {
      fl4 mk[4];
#pragma unroll
      for (int m = 0; m < 4; m++) mk[m] = *(const fl4*)&sM[k0 + (kb << 5) + (m << 3) + (hi << 2)];
#pragma unroll
      for (int r = 0; r < 16; r++)
        p_[kb][r] = fmaf(accs[kb][r], SCALE_LOG2E, mk[r >> 2][r & 3]);
    }
    float mt = p_[0][0];
#pragma unroll
    for (int kb = 0; kb < 2; kb++)
#pragma unroll
      for (int r = 0; r < 16; r++) mt = fmaxf(mt, p_[kb][r]);
    mt = fmaxf(mt, __shfl_xor(mt, 32));
    if (!__all(mt <= mrun + DEFER_THR)) {
      const float mnew = fmaxf(mrun, mt);
      const float fs = exp2f(mrun - mnew);
      lrun *= fs;
#pragma unroll
      for (int r = 0; r < 16; r++) {
        const int qr = (r & 3) + ((r >> 2) << 3) + (hi << 2);
        const float fr = __shfl(fs, (lane & 32) | qr);
#pragma unroll
        for (int db = 0; db < 4; db++) acc2[db][r] *= fr;
      }
      mrun = mnew;
    }
    float ps = 0.f;
#pragma unroll
    for (int kb = 0; kb < 2; kb++)
#pragma unroll
      for (int r = 0; r < 16; r++) {
        const float e = exp2f(p_[kb][r] - mrun);
        p_[kb][r] = e;
        ps += e;
      }
    ps += __shfl_xor(ps, 32);
    lrun += ps;

    bf16x8 pa[4];
#pragma unroll
    for (int kb = 0; kb < 2; kb++)
#pragma unroll
      for (int hh = 0; hh < 2; hh++) {
        const float* pp = &p_[kb][hh << 3];
        const unsigned x01 = cvt_pk_bf16(pp[0], pp[1]);
        const unsigned x23 = cvt_pk_bf16(pp[2], pp[3]);
        const unsigned y01 = cvt_pk_bf16(pp[4], pp[5]);
        const unsigned y23 = cvt_pk_bf16(pp[6], pp[7]);
        const u32x2 sa = __builtin_amdgcn_permlane32_swap(x01, y01, false, false);
        const u32x2 sb = __builtin_amdgcn_permlane32_swap(x23, y23, false, false);
        const u32x4 w = {sa[0], sb[0], sa[1], sb[1]};
        pa[(kb << 1) + hh] = __builtin_bit_cast(bf16x8, w);
      }

    __builtin_amdgcn_s_setprio(1);
#pragma unroll
    for (int db = 0; db < 4; db++) {
      const int dd = ((db & 1) << 5) + l31;
#pragma unroll
      for (int ks = 0; ks < 4; ks++) {
        const int sv = ((db >> 1) << 3) + (ks << 1) + hi;
        const bf16x8 bv = *(const bf16x8*)(sV + (dd << 8) + ((sv ^ (l31 & 15)) << 4));
        acc2[db] = mfma32(pa[ks], bv, acc2[db]);
      }
    }
    __builtin_amdgcn_s_setprio(0);
  };

  STAGE(0, 0);
  __syncthreads();
#pragma unroll 1
  for (int t = 0; t < NT - 1; ++t) {
    STAGE(t + 1, (t + 1) & 1);
    COMPUTE(t, t & 1);
    asm volatile("s_waitcnt vmcnt(0)" ::: "memory");
    __builtin_amdgcn_s_barrier();
    asm volatile("" ::: "memory");
  }
  COMPUTE(NT - 1, (NT - 1) & 1);

  const float inv = 1.f / lrun;
#pragma unroll
  for (int r = 0; r < 16; r++) {
    const int qr = (r & 3) + ((r >> 2) << 3) + (hi << 2);
    const float fr = __shfl(inv, (lane & 32) | qr);
    unsigned short* crow = ctx + (size_t)(b * SEQ + q0w + qr) * HID + h * HDIM + l31;
#pragma unroll
    for (int db = 0; db < 4; db++) crow[db << 5] = f2bf(acc2[db][r] * fr);
  }
}

// ---------------------------------------------------------------- launch
extern "C" void kernel_launch(void* const* d_in, const int* in_sizes, int n_in,
                              void* d_out, int out_size, void* d_ws, size_t ws_size,
                              hipStream_t stream) {
  const float* hs   = (const float*)d_in[0];
  const float* mask = (const float*)d_in[1];
  const float* Wqkv = (const float*)d_in[2];
  const float* bqkv = (const float*)d_in[3];
  const float* Wout = (const float*)d_in[4];
  const float* bout = (const float*)d_in[5];

  char* ws = (char*)d_ws;
  size_t off = 0;
  auto alloc = [&](size_t n) { char* p = ws + off; off += (n + 255) & ~(size_t)255; return p; };
  unsigned short* hs_bf = (unsigned short*)alloc((size_t)MROWS * HID * 2);
  unsigned short* wq_bf = (unsigned short*)alloc((size_t)N3 * HID * 2);
  unsigned short* wo_bf = (unsigned short*)alloc((size_t)HID * HID * 2);
  unsigned short* qkvb  = (unsigned short*)alloc((size_t)MROWS * N3 * 2);
  unsigned short* vtb   = (unsigned short*)alloc((size_t)BATCH * NHEAD * HDIM * SEQ * 2);
  unsigned short* ctxb  = (unsigned short*)alloc((size_t)MROWS * HID * 2);
  (void)ws_size;

  prep_kernel<<<2048 + 12288 + 4096, 256, 0, stream>>>(hs, hs_bf, Wqkv, wq_bf, Wout, wo_bf);
  gemm_ring<true ><<<dim3(N3 / 128, MROWS / 256), 512, 0, stream>>>(hs_bf, wq_bf, bqkv, qkvb, N3);
  transpose_v<<<dim3(SEQ / 64, BATCH * NHEAD), 256, 0, stream>>>(qkvb, vtb);
  attn_kernel<<<512, 256, 0, stream>>>(qkvb, vtb, mask, ctxb);
  gemm_ring<false><<<dim3(HID / 128, MROWS / 256), 512, 0, stream>>>(ctxb, wo_bf, bout, (float*)d_out, HID);
}

// Round 19
// 251.278 us; speedup vs baseline: 1.0647x; 1.0432x over previous
//
#include <hip/hip_runtime.h>
#include <hip/hip_bf16.h>
#include <stdint.h>

typedef __attribute__((ext_vector_type(4)))  float   f32x4;
typedef __attribute__((ext_vector_type(16))) float   f32x16;
typedef __attribute__((ext_vector_type(8)))  __bf16  bf16x8;
typedef __attribute__((ext_vector_type(8)))  short   s16x8;
typedef __attribute__((ext_vector_type(4)))  unsigned short u16x4;
typedef __attribute__((ext_vector_type(4)))  float   fl4;
typedef __attribute__((ext_vector_type(2)))  unsigned int u32x2;
typedef __attribute__((ext_vector_type(4)))  unsigned int u32x4;

#define DEVFN static __device__ __forceinline__

constexpr int BATCH = 2, SEQ = 2048, HID = 2048, NHEAD = 16, HDIM = 128;
constexpr int MROWS = BATCH * SEQ;   // 4096
constexpr int N3    = 3 * HID;       // 6144
constexpr float LOG2E = 1.44269504088896340736f;
constexpr float SCALE_LOG2E = 0.12751649736170852f;   // (1/sqrt(128)) * log2(e)
constexpr float DEFER_THR = 11.541560327111708f;      // 8 * log2(e)

DEVFN unsigned short f2bf(float f) {  // RNE float->bf16
  unsigned int u = __float_as_uint(f);
  u += 0x7FFFu + ((u >> 16) & 1u);
  return (unsigned short)(u >> 16);
}

DEVFN void async_cp16(const void* g, void* l) {
  __builtin_amdgcn_global_load_lds(
      (__attribute__((address_space(1))) void*)g,
      (__attribute__((address_space(3))) void*)l, 16, 0, 0);
}

DEVFN f32x4 mfma_bf16(bf16x8 a, bf16x8 b, f32x4 c) {
  return __builtin_amdgcn_mfma_f32_16x16x32_bf16(a, b, c, 0, 0, 0);
}
DEVFN f32x16 mfma32(bf16x8 a, bf16x8 b, f32x16 c) {
  return __builtin_amdgcn_mfma_f32_32x32x16_bf16(a, b, c, 0, 0, 0);
}
DEVFN unsigned cvt_pk_bf16(float lo, float hi) {
  unsigned r;
  asm("v_cvt_pk_bf16_f32 %0, %1, %2" : "=v"(r) : "v"(lo), "v"(hi));
  return r;
}

// ---------------------------------------------------------------- fused prep (proven r16)
__global__ __launch_bounds__(256) void prep_kernel(const float* __restrict__ hs,
                                                   unsigned short* __restrict__ hs_bf,
                                                   const float* __restrict__ Wqkv,
                                                   unsigned short* __restrict__ wq_bf,
                                                   const float* __restrict__ Wout,
                                                   unsigned short* __restrict__ wo_bf) {
  __shared__ float tile[32][33];
  const int blk = blockIdx.x;
  const int tid = threadIdx.x;
  if (blk < 2048) {
    constexpr int n4 = MROWS * HID / 4;
    for (int i = blk * 256 + tid; i < n4; i += 2048 * 256) {
      fl4 v = ((const fl4*)hs)[i];
      u16x4 hh;
#pragma unroll
      for (int j = 0; j < 4; j++) hh[j] = f2bf(v[j]);
      ((u16x4*)hs_bf)[i] = hh;
    }
    return;
  }
  const bool isQ = blk < 2048 + 12288;
  const int t = isQ ? (blk - 2048) : (blk - 2048 - 12288);
  const int nbx = isQ ? (N3 / 32) : (HID / 32);
  const int C = isQ ? N3 : HID;
  const int R = HID;
  const float* W = isQ ? Wqkv : Wout;
  unsigned short* T = isQ ? wq_bf : wo_bf;
  const int c0 = (t % nbx) * 32, r0 = (t / nbx) * 32;
  const int tx = tid & 31, ty = tid >> 5;
#pragma unroll
  for (int i = 0; i < 4; i++) tile[ty + 8 * i][tx] = W[(size_t)(r0 + ty + 8 * i) * C + c0 + tx];
  __syncthreads();
#pragma unroll
  for (int i = 0; i < 4; i++) {
    const float v = tile[tx][ty + 8 * i];
    T[(size_t)(c0 + ty + 8 * i) * R + r0 + tx] = f2bf(v);
  }
}

// ---------------------------------------------------------------- ring-2 GEMM, BN = 64*NF
// DS-bound fix: per-wave nf = NF output columns share the 8 A ds_reads ->
// DS:MFMA ratio 1.6 (NF=2) -> 2.18 (NF=3). Ring-2 + drain-after-compute
// (attn-r11-proven pattern; STAGE(t+1) loads span COMPUTE(t), drain ~free).
template <int NF, bool OUT_BF16>
__global__ __launch_bounds__(512, 1) void gemm_ring(const unsigned short* __restrict__ A,
                                                    const unsigned short* __restrict__ Bt,
                                                    const float* __restrict__ bias,
                                                    void* __restrict__ Cout, int Ndim) {
  constexpr int KDIM  = 2048;
  constexpr int NT    = KDIM / 64;
  constexpr int BN    = NF * 64;
  constexpr int ASLOT = 256 * 64;          // shorts
  constexpr int BSLOT = BN * 64;
  constexpr int SLOT  = ASLOT + BSLOT;
  __shared__ __align__(16) unsigned short smem[2 * SLOT];  // NF=3: 112 KB, NF=2: 96 KB

  const int tid = threadIdx.x;
  const int wid = tid >> 6, lane = tid & 63;
  const int wm = wid >> 2, wn = wid & 3;
  const int g = lane >> 4, q = lane & 15;
  const int n0 = blockIdx.x * BN, m0 = blockIdx.y * 256;

  const int srow = (wid << 3) + (lane >> 3);
  const int scol = (((lane & 7) ^ (lane >> 3)) << 4);
  const char* gA = (const char*)A  + ((size_t)(m0 + srow) * KDIM) * 2 + scol;
  const char* gB = (const char*)Bt + ((size_t)(n0 + srow) * KDIM) * 2 + scol;
  const int dbase = ((wid << 3)) << 7;

  f32x4 acc[8][NF] = {};
  const int axor = (q & 7) << 4;

  auto STAGE = [&](int tt, int slot) {
    char* sA = (char*)(smem + slot * SLOT);
    char* sB = (char*)(smem + slot * SLOT + ASLOT);
    const size_t koff = (size_t)tt << 7;
#pragma unroll
    for (int i = 0; i < 4; i++)
      async_cp16(gA + (size_t)(i * 64) * (KDIM * 2) + koff, sA + dbase + (i << 13));
#pragma unroll
    for (int i = 0; i < NF; i++)
      async_cp16(gB + (size_t)(i * 64) * (KDIM * 2) + koff, sB + dbase + (i << 13));
  };

  auto COMPUTE = [&](int slot) {
    const char* sA = (const char*)(smem + slot * SLOT);
    const char* sB = (const char*)(smem + slot * SLOT + ASLOT);
#pragma unroll
    for (int ks = 0; ks < 2; ks++) {
      const int kb = (ks << 6) + (g << 4);
      bf16x8 av[8], bv[NF];
#pragma unroll
      for (int nf = 0; nf < NF; nf++) {
        const int row = (wn * NF + nf) * 16 + q;
        bv[nf] = *(const bf16x8*)(sB + (row << 7) + (kb ^ axor));
      }
#pragma unroll
      for (int mf = 0; mf < 8; mf++) {
        const int row = (wm << 7) + (mf << 4) + q;
        av[mf] = *(const bf16x8*)(sA + (row << 7) + (kb ^ axor));
      }
#pragma unroll
      for (int mf = 0; mf < 8; mf++)
#pragma unroll
        for (int nf = 0; nf < NF; nf++)
          acc[mf][nf] = mfma_bf16(av[mf], bv[nf], acc[mf][nf]);
    }
  };

  STAGE(0, 0);
  __syncthreads();          // drains prologue loads + barrier
#pragma unroll 1
  for (int t = 0; t < NT - 1; ++t) {
    STAGE(t + 1, (t + 1) & 1);
    COMPUTE(t & 1);
    asm volatile("s_waitcnt vmcnt(0)" ::: "memory");
    __builtin_amdgcn_s_barrier();
    asm volatile("" ::: "memory");
  }
  COMPUTE((NT - 1) & 1);

  float bvv[NF];
#pragma unroll
  for (int nf = 0; nf < NF; nf++) bvv[nf] = bias[n0 + (wn * NF + nf) * 16 + q];
#pragma unroll
  for (int mf = 0; mf < 8; mf++) {
    const int rowg = m0 + (wm << 7) + (mf << 4) + (g << 2);
#pragma unroll
    for (int nf = 0; nf < NF; nf++) {
      const int colg = n0 + (wn * NF + nf) * 16 + q;
#pragma unroll
      for (int r = 0; r < 4; r++) {
        const float v = acc[mf][nf][r] + bvv[nf];
        if (OUT_BF16)
          ((unsigned short*)Cout)[(size_t)(rowg + r) * Ndim + colg] = f2bf(v);
        else
          ((float*)Cout)[(size_t)(rowg + r) * Ndim + colg] = v;
      }
    }
  }
}

// ---------------------------------------------------------------- V slice of QKV -> V^T [z][d][s]
__global__ __launch_bounds__(256) void transpose_v(const unsigned short* __restrict__ qkv,
                                                   unsigned short* __restrict__ vt) {
  __shared__ __align__(16) unsigned short tile[64][136];
  const int z = blockIdx.y, b = z >> 4, h = z & 15;
  const int s0 = blockIdx.x << 6;
  const int t = threadIdx.x;
#pragma unroll
  for (int i = 0; i < 4; i++) {
    const int idx = t + (i << 8);
    const int row = idx >> 4, ch = idx & 15;
    *(s16x8*)&tile[row][ch << 3] =
        *(const s16x8*)(qkv + (size_t)(b * SEQ + s0 + row) * N3 + 2 * HID + h * HDIM + (ch << 3));
  }
  __syncthreads();
#pragma unroll
  for (int i = 0; i < 4; i++) {
    const int idx = t + (i << 8);
    const int d = idx >> 3, sc = idx & 7;
    s16x8 v;
#pragma unroll
    for (int j = 0; j < 8; j++) v[j] = (short)tile[(sc << 3) + j][d];
    *(s16x8*)(vt + (size_t)(z * HDIM + d) * SEQ + s0 + (sc << 3)) = v;
  }
}

// ---------------------------------------------------------------- flash attention v3 (proven r11)
__global__ __launch_bounds__(256, 2) void attn_kernel(const unsigned short* __restrict__ qkv,
                                                      const unsigned short* __restrict__ vt,
                                                      const float* __restrict__ mask,
                                                      unsigned short* __restrict__ ctx) {
  constexpr int NT    = SEQ / 64;
  constexpr int KSLOT = 64 * 128;
  constexpr int VSLOT = 64 * 128;
  constexpr int SLOT  = KSLOT + VSLOT;
  __shared__ __align__(16) unsigned short sKV[2 * SLOT];   // 64 KB
  __shared__ __align__(16) float sM[SEQ];                  // 8 KB

  const int bid = blockIdx.x;
  const int idx = bid >> 3;
  const int z  = ((bid & 7) << 2) + (idx >> 4);
  const int qb = idx & 15;
  const int b = z >> 4, h = z & 15;
  const int tid = threadIdx.x, wid = tid >> 6, lane = tid & 63;
  const int l31 = lane & 31, hi = lane >> 5;
  const int q0w = (qb << 7) + (wid << 5);

#pragma unroll
  for (int j = 0; j < 2; j++) {
    fl4 m = ((const fl4*)(mask + (size_t)b * SEQ))[tid + (j << 8)];
    m *= LOG2E;
    ((fl4*)sM)[tid + (j << 8)] = m;
  }

  bf16x8 bq[8];
  {
    const char* qrow = (const char*)(qkv + (size_t)(b * SEQ + q0w + l31) * N3 + h * HDIM);
#pragma unroll
    for (int kc = 0; kc < 8; kc++) bq[kc] = *(const bf16x8*)(qrow + (kc << 5) + (hi << 4));
  }

  f32x16 acc2[4] = {};
  float mrun = -1e30f, lrun = 0.f;

  const char* gK = (const char*)qkv + ((size_t)(b * SEQ) * N3 + HID + h * HDIM) * 2;
  const char* gV = (const char*)vt + ((size_t)z * HDIM * SEQ) * 2;

  auto STAGE = [&](int tt, int slot) {
    char* kb_ = (char*)(sKV + slot * SLOT);
    char* vb_ = kb_ + KSLOT * 2;
    const int k0 = tt << 6;
#pragma unroll
    for (int i = 0; i < 4; i++) {
      const int row = (i << 4) + (wid << 2) + (lane >> 4);
      const int sl  = lane & 15;
      const int dst = (i << 12) + (wid << 10);
      async_cp16(gK + ((size_t)(k0 + row) * N3) * 2 + (((sl ^ (row & 15))) << 4), kb_ + dst);
      const int sv  = sl ^ (row & 15);
      const int dhi = sv >> 3, kc8 = sv & 7;
      async_cp16(gV + ((size_t)((dhi << 6) + row) * SEQ + k0 + (kc8 << 3)) * 2, vb_ + dst);
    }
  };

  auto COMPUTE = [&](int t, int slot) {
    const char* sK = (const char*)(sKV + slot * SLOT);
    const char* sV = (const char*)(sKV + slot * SLOT + KSLOT);
    const int k0 = t << 6;

    f32x16 accs[2] = {};
    __builtin_amdgcn_s_setprio(1);
#pragma unroll
    for (int kb = 0; kb < 2; kb++)
#pragma unroll
      for (int kc = 0; kc < 8; kc++) {
        const int key = (kb << 5) + l31;
        const bf16x8 ka = *(const bf16x8*)(sK + (key << 8) +
                                           ((((kc << 1) + hi) ^ (l31 & 15)) << 4));
        accs[kb] = mfma32(ka, bq[kc], accs[kb]);
      }
    __builtin_amdgcn_s_setprio(0);

    float p_[2][16];
#pragma unroll
    for (int kb = 0; kb < 2; kb++) {
      fl4 mk[4];
#pragma unroll
      for (int m = 0; m < 4; m++) mk[m] = *(const fl4*)&sM[k0 + (kb << 5) + (m << 3) + (hi << 2)];
#pragma unroll
      for (int r = 0; r < 16; r++)
        p_[kb][r] = fmaf(accs[kb][r], SCALE_LOG2E, mk[r >> 2][r & 3]);
    }
    float mt = p_[0][0];
#pragma unroll
    for (int kb = 0; kb < 2; kb++)
#pragma unroll
      for (int r = 0; r < 16; r++) mt = fmaxf(mt, p_[kb][r]);
    mt = fmaxf(mt, __shfl_xor(mt, 32));
    if (!__all(mt <= mrun + DEFER_THR)) {
      const float mnew = fmaxf(mrun, mt);
      const float fs = exp2f(mrun - mnew);
      lrun *= fs;
#pragma unroll
      for (int r = 0; r < 16; r++) {
        const int qr = (r & 3) + ((r >> 2) << 3) + (hi << 2);
        const float fr = __shfl(fs, (lane & 32) | qr);
#pragma unroll
        for (int db = 0; db < 4; db++) acc2[db][r] *= fr;
      }
      mrun = mnew;
    }
    float ps = 0.f;
#pragma unroll
    for (int kb = 0; kb < 2; kb++)
#pragma unroll
      for (int r = 0; r < 16; r++) {
        const float e = exp2f(p_[kb][r] - mrun);
        p_[kb][r] = e;
        ps += e;
      }
    ps += __shfl_xor(ps, 32);
    lrun += ps;

    bf16x8 pa[4];
#pragma unroll
    for (int kb = 0; kb < 2; kb++)
#pragma unroll
      for (int hh = 0; hh < 2; hh++) {
        const float* pp = &p_[kb][hh << 3];
        const unsigned x01 = cvt_pk_bf16(pp[0], pp[1]);
        const unsigned x23 = cvt_pk_bf16(pp[2], pp[3]);
        const unsigned y01 = cvt_pk_bf16(pp[4], pp[5]);
        const unsigned y23 = cvt_pk_bf16(pp[6], pp[7]);
        const u32x2 sa = __builtin_amdgcn_permlane32_swap(x01, y01, false, false);
        const u32x2 sb = __builtin_amdgcn_permlane32_swap(x23, y23, false, false);
        const u32x4 w = {sa[0], sb[0], sa[1], sb[1]};
        pa[(kb << 1) + hh] = __builtin_bit_cast(bf16x8, w);
      }

    __builtin_amdgcn_s_setprio(1);
#pragma unroll
    for (int db = 0; db < 4; db++) {
      const int dd = ((db & 1) << 5) + l31;
#pragma unroll
      for (int ks = 0; ks < 4; ks++) {
        const int sv = ((db >> 1) << 3) + (ks << 1) + hi;
        const bf16x8 bv = *(const bf16x8*)(sV + (dd << 8) + ((sv ^ (l31 & 15)) << 4));
        acc2[db] = mfma32(pa[ks], bv, acc2[db]);
      }
    }
    __builtin_amdgcn_s_setprio(0);
  };

  STAGE(0, 0);
  __syncthreads();
#pragma unroll 1
  for (int t = 0; t < NT - 1; ++t) {
    STAGE(t + 1, (t + 1) & 1);
    COMPUTE(t, t & 1);
    asm volatile("s_waitcnt vmcnt(0)" ::: "memory");
    __builtin_amdgcn_s_barrier();
    asm volatile("" ::: "memory");
  }
  COMPUTE(NT - 1, (NT - 1) & 1);

  const float inv = 1.f / lrun;
#pragma unroll
  for (int r = 0; r < 16; r++) {
    const int qr = (r & 3) + ((r >> 2) << 3) + (hi << 2);
    const float fr = __shfl(inv, (lane & 32) | qr);
    unsigned short* crow = ctx + (size_t)(b * SEQ + q0w + qr) * HID + h * HDIM + l31;
#pragma unroll
    for (int db = 0; db < 4; db++) crow[db << 5] = f2bf(acc2[db][r] * fr);
  }
}

// ---------------------------------------------------------------- launch
extern "C" void kernel_launch(void* const* d_in, const int* in_sizes, int n_in,
                              void* d_out, int out_size, void* d_ws, size_t ws_size,
                              hipStream_t stream) {
  const float* hs   = (const float*)d_in[0];
  const float* mask = (const float*)d_in[1];
  const float* Wqkv = (const float*)d_in[2];
  const float* bqkv = (const float*)d_in[3];
  const float* Wout = (const float*)d_in[4];
  const float* bout = (const float*)d_in[5];

  char* ws = (char*)d_ws;
  size_t off = 0;
  auto alloc = [&](size_t n) { char* p = ws + off; off += (n + 255) & ~(size_t)255; return p; };
  unsigned short* hs_bf = (unsigned short*)alloc((size_t)MROWS * HID * 2);
  unsigned short* wq_bf = (unsigned short*)alloc((size_t)N3 * HID * 2);
  unsigned short* wo_bf = (unsigned short*)alloc((size_t)HID * HID * 2);
  unsigned short* qkvb  = (unsigned short*)alloc((size_t)MROWS * N3 * 2);
  unsigned short* vtb   = (unsigned short*)alloc((size_t)BATCH * NHEAD * HDIM * SEQ * 2);
  unsigned short* ctxb  = (unsigned short*)alloc((size_t)MROWS * HID * 2);
  (void)ws_size;

  prep_kernel<<<2048 + 12288 + 4096, 256, 0, stream>>>(hs, hs_bf, Wqkv, wq_bf, Wout, wo_bf);
  gemm_ring<3, true ><<<dim3(N3 / 192, MROWS / 256), 512, 0, stream>>>(hs_bf, wq_bf, bqkv, qkvb, N3);
  transpose_v<<<dim3(SEQ / 64, BATCH * NHEAD), 256, 0, stream>>>(qkvb, vtb);
  attn_kernel<<<512, 256, 0, stream>>>(qkvb, vtb, mask, ctxb);
  gemm_ring<2, false><<<dim3(HID / 128, MROWS / 256), 512, 0, stream>>>(ctxb, wo_bf, bout, (float*)d_out, HID);
}